// Round 1
// baseline (867.739 us; speedup 1.0000x reference)
//
#include <hip/hip_runtime.h>

// 3x3 conv, pad=1, stride=1, NHWC fp32 -> implicit GEMM:
//   M = 32*56*56 = 100352 (img,oh,ow), N = 256 (cout), K = 9*128 = 1152 (fh,fw,ci)
//   A[m][k] = im2col(input), B[k][n] = weight (HWIO is already K-major, n-fastest)
// fp32 vector-ALU baseline (no fp32 MFMA on CDNA4). 64x64 tile, BK=32,
// 4x4 register tile per thread, 256 threads/block.

#define NIMG 32
#define HH 56
#define WW 56
#define CIN 128
#define COUT 256
#define KTOT 1152   // 9 * 128

#define BM 64
#define BN 64
#define BK 32
#define LDSS 68     // LDS leading stride (floats): 16B-aligned + conflict-friendly

__global__ __launch_bounds__(256) void conv_gemm_f32(
    const float* __restrict__ in,    // (32,56,56,128)
    const float* __restrict__ wgt,   // (3,3,128,256) = (K=1152, N=256) row-major
    const float* __restrict__ bias,  // (256)
    float* __restrict__ out)         // (32,56,56,256)
{
    __shared__ float As[BK * LDSS];  // [k][m], stride LDSS
    __shared__ float Bs[BK * LDSS];  // [k][n], stride LDSS

    const int t  = threadIdx.x;
    const int m0 = blockIdx.y * BM;
    const int n0 = blockIdx.x * BN;

    // ---- A-load mapping: thread -> (row am, k-quad kq); loads k=kq*4..+3 and +16
    const int am = t >> 2;   // 0..63
    const int kq = t & 3;    // 0..3
    const int gm  = m0 + am;
    const int img = gm / (HH * WW);
    const int rem = gm % (HH * WW);
    const int oh  = rem / WW;
    const int ow  = rem % WW;

    // ---- B-load mapping: thread -> (k-row bk / bk+16, float4 col bn4)
    const int bk  = t >> 4;  // 0..15
    const int bn4 = t & 15;  // 0..15

    // ---- compute mapping: 16x16 thread grid, 4x4 tile each
    const int tx = t & 15;   // col group
    const int ty = t >> 4;   // row group

    float acc[4][4];
#pragma unroll
    for (int i = 0; i < 4; ++i)
#pragma unroll
        for (int j = 0; j < 4; ++j) acc[i][j] = 0.f;

    for (int kt = 0; kt < KTOT / BK; ++kt) {
        const int k0  = kt * BK;
        const int fhw = k0 >> 7;     // k0 / 128 : (fh,fw) constant across the 32-k tile
        const int ci0 = k0 & 127;
        const int fh  = fhw / 3;
        const int fw  = fhw - fhw / 3 * 3;
        const int ih  = oh + fh - 1;
        const int iw  = ow + fw - 1;
        const bool valid = ((unsigned)ih < HH) && ((unsigned)iw < WW);

        float4 a0 = make_float4(0.f, 0.f, 0.f, 0.f), a1 = a0;
        if (valid) {
            const float* p = in + ((((size_t)img * HH + ih) * WW + iw) * CIN + ci0);
            a0 = *(const float4*)(p + kq * 4);
            a1 = *(const float4*)(p + kq * 4 + 16);
        }
        const float* wp = wgt + (size_t)(k0 + bk) * COUT + n0 + bn4 * 4;
        const float4 b0 = *(const float4*)(wp);
        const float4 b1 = *(const float4*)(wp + 16 * COUT);

        __syncthreads();
        {
            const int ka = kq * 4;
            As[(ka + 0)  * LDSS + am] = a0.x;
            As[(ka + 1)  * LDSS + am] = a0.y;
            As[(ka + 2)  * LDSS + am] = a0.z;
            As[(ka + 3)  * LDSS + am] = a0.w;
            As[(ka + 16) * LDSS + am] = a1.x;
            As[(ka + 17) * LDSS + am] = a1.y;
            As[(ka + 18) * LDSS + am] = a1.z;
            As[(ka + 19) * LDSS + am] = a1.w;
        }
        *(float4*)&Bs[bk        * LDSS + bn4 * 4] = b0;
        *(float4*)&Bs[(bk + 16) * LDSS + bn4 * 4] = b1;
        __syncthreads();

#pragma unroll
        for (int k = 0; k < BK; ++k) {
            const float4 av = *(const float4*)&As[k * LDSS + ty * 4];
            const float4 bv = *(const float4*)&Bs[k * LDSS + tx * 4];
            const float ar[4] = {av.x, av.y, av.z, av.w};
            const float br[4] = {bv.x, bv.y, bv.z, bv.w};
#pragma unroll
            for (int i = 0; i < 4; ++i)
#pragma unroll
                for (int j = 0; j < 4; ++j)
                    acc[i][j] = fmaf(ar[i], br[j], acc[i][j]);
        }
    }

    // ---- epilogue: bias + ReLU, coalesced float4 stores (n is fastest dim)
    const int n = n0 + tx * 4;
    const float4 bv = *(const float4*)(bias + n);
#pragma unroll
    for (int i = 0; i < 4; ++i) {
        const size_t gmo = (size_t)(m0 + ty * 4 + i);
        float4 r;
        r.x = fmaxf(acc[i][0] + bv.x, 0.f);
        r.y = fmaxf(acc[i][1] + bv.y, 0.f);
        r.z = fmaxf(acc[i][2] + bv.z, 0.f);
        r.w = fmaxf(acc[i][3] + bv.w, 0.f);
        *(float4*)(out + gmo * COUT + n) = r;
    }
}

extern "C" void kernel_launch(void* const* d_in, const int* in_sizes, int n_in,
                              void* d_out, int out_size, void* d_ws, size_t ws_size,
                              hipStream_t stream) {
    const float* in   = (const float*)d_in[0];
    const float* wgt  = (const float*)d_in[1];
    const float* bias = (const float*)d_in[2];
    float* out = (float*)d_out;

    dim3 grid(COUT / BN, (NIMG * HH * WW) / BM);  // (4, 1568)
    conv_gemm_f32<<<grid, dim3(256), 0, stream>>>(in, wgt, bias, out);
}

// Round 2
// 224.079 us; speedup vs baseline: 3.8725x; 3.8725x over previous
//
#include <hip/hip_runtime.h>
#include <hip/hip_bf16.h>

// 3x3 conv pad=1 stride=1, NHWC fp32 -> bf16 MFMA implicit GEMM.
//   M = 32*56*56 = 100352, N = 256 (cout), K = 9*128 = 1152
// Pipeline: pack_input (fp32 -> padded bf16, zero halo) + pack_wgt (HWIO ->
// [n][k] bf16 transpose) + conv_mfma (m97-style 128x128 tile, BK=32,
// global_load_lds width-16 staging, 16x16x32 bf16 MFMA).

#define NIMG 32
#define HH 56
#define WW 56
#define PH 58
#define PW 58
#define CIN 128
#define COUT 256
#define KTOT 1152
#define PAD_ELEMS (NIMG * PH * PW * CIN)  // 13,778,944 bf16

typedef __attribute__((ext_vector_type(8))) short bf16x8;   // 8 bf16 = 4 VGPRs
typedef __attribute__((ext_vector_type(4))) short s16x4;
typedef __attribute__((ext_vector_type(4))) float f32x4;

__device__ __forceinline__ short f2bf(float x) {
    union { __hip_bfloat16 b; short s; } u;
    u.b = __float2bfloat16(x);  // RNE
    return u.s;
}

typedef const void __attribute__((address_space(1)))* gas1_t;
typedef void __attribute__((address_space(3)))* las3_t;
__device__ __forceinline__ void async16(short* lds, const short* g) {
    // LDS dest = wave-uniform base + lane*16 (pass wave-uniform lds!)
    __builtin_amdgcn_global_load_lds((gas1_t)g, (las3_t)lds, 16, 0, 0);
}

// ---- pack 1: fp32 NHWC -> padded bf16 (32,58,58,128), zero halo -------------
__global__ __launch_bounds__(256) void pack_input(const float* __restrict__ in,
                                                  short* __restrict__ pad) {
    const int tid  = blockIdx.x * 256 + threadIdx.x;
    const int flat = tid * 8;                  // 8 bf16 per thread
    const int c8   = flat & (CIN - 1);
    const int rest = flat >> 7;
    const int iw   = rest % PW;
    const int r2   = rest / PW;
    const int ih   = r2 % PH;
    const int img  = r2 / PH;
    bf16x8 v = (bf16x8)0;
    if (ih >= 1 && ih <= HH && iw >= 1 && iw <= WW) {
        const float* p = in + (((size_t)(img * HH + ih - 1) * WW + (iw - 1)) * CIN + c8);
        const float4 x0 = *(const float4*)p;
        const float4 x1 = *(const float4*)(p + 4);
        v.s0 = f2bf(x0.x); v.s1 = f2bf(x0.y); v.s2 = f2bf(x0.z); v.s3 = f2bf(x0.w);
        v.s4 = f2bf(x1.x); v.s5 = f2bf(x1.y); v.s6 = f2bf(x1.z); v.s7 = f2bf(x1.w);
    }
    *(bf16x8*)(pad + flat) = v;
}

// ---- pack 2: weights (K=1152, N=256) fp32 -> bf16 transposed [n][k] ---------
__global__ __launch_bounds__(256) void pack_wgt(const float* __restrict__ w,
                                                short* __restrict__ wt) {
    __shared__ short tile[32][33];  // +1 pad breaks bank conflicts
    const int k0 = blockIdx.x * 32;  // 36
    const int n0 = blockIdx.y * 32;  // 8
    const int t  = threadIdx.x;
    {
        const int kl  = t >> 3;        // 0..31
        const int nl4 = (t & 7) * 4;   // 0..28
        const float4 x = *(const float4*)(w + (size_t)(k0 + kl) * COUT + n0 + nl4);
        tile[kl][nl4 + 0] = f2bf(x.x);
        tile[kl][nl4 + 1] = f2bf(x.y);
        tile[kl][nl4 + 2] = f2bf(x.z);
        tile[kl][nl4 + 3] = f2bf(x.w);
    }
    __syncthreads();
    {
        const int nl  = t >> 3;
        const int kl4 = (t & 7) * 4;
        s16x4 v;
        v.x = tile[kl4 + 0][nl];
        v.y = tile[kl4 + 1][nl];
        v.z = tile[kl4 + 2][nl];
        v.w = tile[kl4 + 3][nl];
        *(s16x4*)(wt + (size_t)(n0 + nl) * KTOT + k0 + kl4) = v;
    }
}

// ---- GEMM: 128x128 tile, BK=32, 4 waves, 16x16x32 bf16 MFMA ----------------
__global__ __launch_bounds__(256) void conv_mfma(const short* __restrict__ apad,
                                                 const short* __restrict__ bwt,
                                                 const float* __restrict__ bias,
                                                 float* __restrict__ out) {
    __shared__ short As[128 * 32];  // [m][k], k contiguous (chunk order = stage order)
    __shared__ short Bs[128 * 32];  // [n][k]

    const int t  = threadIdx.x;
    const int l  = t & 63;
    const int w  = t >> 6;
    const int m0 = blockIdx.y * 128;
    const int n0 = blockIdx.x * 128;

    // ---- staging map: thread t, half j -> chunk c = j*256 + t
    //      chunk c = (row c>>2, k-chunk c&3); LDS bytes [c*16, c*16+16)
    const int kchunk = t & 3;
    const int row0   = t >> 2;  // + j*64
    int abase[2], bbase[2];
#pragma unroll
    for (int j = 0; j < 2; ++j) {
        const int m   = m0 + row0 + j * 64;
        const int img = m / (HH * WW);
        const int rem = m - img * (HH * WW);
        const int oh  = rem / WW;
        const int ow  = rem - oh * WW;
        abase[j] = ((img * PH + oh) * PW + ow) * CIN + kchunk * 8;  // fh=fw=0 base
        bbase[j] = (n0 + row0 + j * 64) * KTOT + kchunk * 8;
    }

    f32x4 acc[4][4];
#pragma unroll
    for (int i = 0; i < 4; ++i)
#pragma unroll
        for (int j = 0; j < 4; ++j) { f32x4 z = {0.f, 0.f, 0.f, 0.f}; acc[i][j] = z; }

    const int wm = w & 1;      // wave's 64-row block
    const int wn = w >> 1;     // wave's 64-col block
    const int fr = l & 15;     // fragment row/col within 16
    const int fq = l >> 4;     // k-quad / output row group

    for (int kt = 0; kt < KTOT / 32; ++kt) {
        const int fhw  = kt >> 2;            // (fh,fw) plane: 128 ci / 32 = 4 tiles each
        const int ci0  = (kt & 3) * 32;
        const int fh   = fhw / 3;
        const int fw   = fhw - fh * 3;
        const int aoff = (fh * PW + fw) * CIN + ci0;  // padded-input k offset
        const int boff = kt * 32;

        __syncthreads();  // previous tile's LDS reads done
#pragma unroll
        for (int j = 0; j < 2; ++j) {
            async16(As + (j * 256 + w * 64) * 8, apad + abase[j] + aoff);
            async16(Bs + (j * 256 + w * 64) * 8, bwt + bbase[j] + boff);
        }
        __syncthreads();  // staging visible (compiler inserts vmcnt(0))

        bf16x8 af[4], bf[4];
#pragma unroll
        for (int i = 0; i < 4; ++i)
            af[i] = *(bf16x8*)&As[(wm * 64 + i * 16 + fr) * 32 + fq * 8];
#pragma unroll
        for (int j = 0; j < 4; ++j)
            bf[j] = *(bf16x8*)&Bs[(wn * 64 + j * 16 + fr) * 32 + fq * 8];
#pragma unroll
        for (int i = 0; i < 4; ++i)
#pragma unroll
            for (int j = 0; j < 4; ++j)
                acc[i][j] = __builtin_amdgcn_mfma_f32_16x16x32_bf16(af[i], bf[j], acc[i][j], 0, 0, 0);
    }

    // ---- epilogue: bias + ReLU. D: col(N)=lane&15, row(M)=quad*4+reg (m89)
#pragma unroll
    for (int j = 0; j < 4; ++j) {
        const int n  = n0 + wn * 64 + j * 16 + fr;
        const float bj = bias[n];
#pragma unroll
        for (int i = 0; i < 4; ++i) {
            const int mrow = m0 + wm * 64 + i * 16 + fq * 4;
#pragma unroll
            for (int r = 0; r < 4; ++r) {
                const float v = acc[i][j][r] + bj;
                out[(size_t)(mrow + r) * COUT + n] = v > 0.f ? v : 0.f;
            }
        }
    }
}

extern "C" void kernel_launch(void* const* d_in, const int* in_sizes, int n_in,
                              void* d_out, int out_size, void* d_ws, size_t ws_size,
                              hipStream_t stream) {
    const float* in   = (const float*)d_in[0];
    const float* wgt  = (const float*)d_in[1];
    const float* bias = (const float*)d_in[2];
    float* out = (float*)d_out;

    short* pad = (short*)d_ws;                       // 27,557,888 B
    short* wt  = (short*)d_ws + PAD_ELEMS;           // + 589,824 B (16B-aligned)

    pack_input<<<PAD_ELEMS / 8 / 256, 256, 0, stream>>>(in, pad);
    pack_wgt<<<dim3(KTOT / 32, COUT / 32), 256, 0, stream>>>(wgt, wt);

    dim3 grid(COUT / 128, (NIMG * HH * WW) / 128);   // (2, 784)
    conv_mfma<<<grid, 256, 0, stream>>>(pad, wt, bias, out);
}